// Round 3
// baseline (2031.598 us; speedup 1.0000x reference)
//
#include <hip/hip_runtime.h>
#include <math.h>

constexpr int THREADS = 128;
constexpr int RSTR = 99;   // per-thread LDS row (floats); odd -> bank-spread

__device__ __forceinline__ float sigm(float x) { return 1.0f / (1.0f + __expf(-x)); }

// rank-4 update of acc[64] from one float4 of x and 4 weight rows (uniform addr -> s_load)
#define RANK4(XV, WPTR) do {                                                            \
    const float* w_ = (WPTR);                                                           \
    _Pragma("unroll") for (int o_ = 0; o_ < 64; ++o_) acc[o_] = fmaf((XV).x, w_[o_],       acc[o_]); \
    _Pragma("unroll") for (int o_ = 0; o_ < 64; ++o_) acc[o_] = fmaf((XV).y, w_[64 + o_],  acc[o_]); \
    _Pragma("unroll") for (int o_ = 0; o_ < 64; ++o_) acc[o_] = fmaf((XV).z, w_[128 + o_], acc[o_]); \
    _Pragma("unroll") for (int o_ = 0; o_ < 64; ++o_) acc[o_] = fmaf((XV).w, w_[192 + o_], acc[o_]); \
} while (0)

__global__ __launch_bounds__(THREADS) void gvp_edge_kernel(
    const float* __restrict__ node_s, const float* __restrict__ node_v,
    const int* __restrict__ ei, const float* __restrict__ edge_s,
    const float* __restrict__ edge_v,
    const float* __restrict__ w1_wh, const float* __restrict__ w1_ws,
    const float* __restrict__ w1_wsb, const float* __restrict__ w1_wv,
    const float* __restrict__ w1_wsv, const float* __restrict__ w1_wsvb,
    const float* __restrict__ w2_wh, const float* __restrict__ w2_ws,
    const float* __restrict__ w2_wsb, const float* __restrict__ w2_wv,
    const float* __restrict__ w2_wsv, const float* __restrict__ w2_wsvb,
    const float* __restrict__ w3_wh, const float* __restrict__ w3_ws,
    const float* __restrict__ w3_wsb, const float* __restrict__ w3_wv,
    const float* __restrict__ w3_wsv, const float* __restrict__ w3_wsvb,
    float* __restrict__ out_s,   // [N][64] accumulators (in d_out)
    float* __restrict__ out_v,   // [N][12] accumulators (in d_out)
    float* __restrict__ cnt,     // [N]
    int E)
{
    __shared__ float rows[THREADS * RSTR];
    float* row = rows + threadIdx.x * RSTR;   // this thread's private row
    const int e = blockIdx.x * THREADS + threadIdx.x;
    if (e >= E) return;
    const int src = ei[e];
    const int dst = ei[E + e];

    // ---- A: stage v_msg into LDS row.
    // layout: row[0..47] = node_v[src] (flat c*3+d, c=0..15)
    //         row[48..95] = node_v[dst] (c=17..32 -> slot 48+3*(c-17)+d)
    //         row[96..98] = edge_v      (c=16)
    {
        const float* a = node_v + (size_t)src * 48;
        const float* b = node_v + (size_t)dst * 48;
#pragma unroll
        for (int j = 0; j < 48; j += 4) {
            float4 va = *(const float4*)(a + j);
            row[j + 0] = va.x; row[j + 1] = va.y; row[j + 2] = va.z; row[j + 3] = va.w;
            float4 vb = *(const float4*)(b + j);
            row[48 + j + 0] = vb.x; row[48 + j + 1] = vb.y; row[48 + j + 2] = vb.z; row[48 + j + 3] = vb.w;
        }
        row[96] = edge_v[(size_t)e * 3 + 0];
        row[97] = edge_v[(size_t)e * 3 + 1];
        row[98] = edge_v[(size_t)e * 3 + 2];
    }

    // ---- B: vh = v_msg^T @ w1_wh  (per h: 3-vector), vn1[33], pv[12] = vh @ w1_wv.
    float vn[33];
    float pv[12];
#pragma unroll
    for (int i = 0; i < 12; ++i) pv[i] = 0.0f;
#pragma unroll
    for (int p = 0; p < 3; ++p) {            // h in 3 blocks of 11
        const int h0 = p * 11;
        float a0[11], a1[11], a2[11];
#pragma unroll
        for (int i = 0; i < 11; ++i) { a0[i] = 0.f; a1[i] = 0.f; a2[i] = 0.f; }
        // src channels c = 0..15
        for (int c = 0; c < 16; ++c) {
            const float v0 = row[3 * c + 0], v1 = row[3 * c + 1], v2 = row[3 * c + 2];
            const float* wr = w1_wh + c * 33 + h0;
#pragma unroll
            for (int i = 0; i < 11; ++i) {
                const float w = wr[i];
                a0[i] = fmaf(v0, w, a0[i]); a1[i] = fmaf(v1, w, a1[i]); a2[i] = fmaf(v2, w, a2[i]);
            }
        }
        // dst channels c = 17..32
        for (int c = 0; c < 16; ++c) {
            const float v0 = row[48 + 3 * c + 0], v1 = row[48 + 3 * c + 1], v2 = row[48 + 3 * c + 2];
            const float* wr = w1_wh + (17 + c) * 33 + h0;
#pragma unroll
            for (int i = 0; i < 11; ++i) {
                const float w = wr[i];
                a0[i] = fmaf(v0, w, a0[i]); a1[i] = fmaf(v1, w, a1[i]); a2[i] = fmaf(v2, w, a2[i]);
            }
        }
        // edge channel c = 16
        {
            const float v0 = row[96], v1 = row[97], v2 = row[98];
            const float* wr = w1_wh + 16 * 33 + h0;
#pragma unroll
            for (int i = 0; i < 11; ++i) {
                const float w = wr[i];
                a0[i] = fmaf(v0, w, a0[i]); a1[i] = fmaf(v1, w, a1[i]); a2[i] = fmaf(v2, w, a2[i]);
            }
        }
#pragma unroll
        for (int i = 0; i < 11; ++i) {
            const int h = h0 + i;
            vn[h] = sqrtf(fmaxf(a0[i] * a0[i] + a1[i] * a1[i] + a2[i] * a2[i], 1e-8f));
#pragma unroll
            for (int vo = 0; vo < 4; ++vo) {
                const float w = w1_wv[h * 4 + vo];
                pv[vo * 3 + 0] = fmaf(a0[i], w, pv[vo * 3 + 0]);
                pv[vo * 3 + 1] = fmaf(a1[i], w, pv[vo * 3 + 1]);
                pv[vo * 3 + 2] = fmaf(a2[i], w, pv[vo * 3 + 2]);
            }
        }
    }
    // vm dead -> park vn in row[0..32] so the vn-GEMM below stays a rolled loop
#pragma unroll
    for (int h = 0; h < 33; ++h) row[h] = vn[h];

    // ---- C: GEMM1  s1[o] = sum_k x1[k]*w1_ws[k][o],
    //        x1 = [node_s[src](0..127) | edge_s(128..159) | node_s[dst](160..287) | vn1(288..320)]
    float acc[64];
#pragma unroll
    for (int o = 0; o < 64; ++o) acc[o] = 0.0f;
    {
        const float4* xs = (const float4*)(node_s + (size_t)src * 128);
        for (int k4 = 0; k4 < 32; ++k4) { float4 x = xs[k4]; RANK4(x, w1_ws + (k4 * 4) * 64); }
    }
    {
        const float4* xs = (const float4*)(edge_s + (size_t)e * 32);
        for (int k4 = 0; k4 < 8; ++k4)  { float4 x = xs[k4]; RANK4(x, w1_ws + (128 + k4 * 4) * 64); }
    }
    {
        const float4* xs = (const float4*)(node_s + (size_t)dst * 128);
        for (int k4 = 0; k4 < 32; ++k4) { float4 x = xs[k4]; RANK4(x, w1_ws + (160 + k4 * 4) * 64); }
    }
    for (int h = 0; h < 33; ++h) {
        const float xk = row[h];
        const float* w = w1_ws + (288 + h) * 64;
#pragma unroll
        for (int o = 0; o < 64; ++o) acc[o] = fmaf(xk, w[o], acc[o]);
    }

    // ---- D: layer-1 epilogue: gate1 (sigmoid(s1) @ wsv), relu -> row[0..63], vn2 -> row[64..67]
    float gp[4] = {0.f, 0.f, 0.f, 0.f};
#pragma unroll
    for (int o = 0; o < 64; ++o) {
        const float s = acc[o] + w1_wsb[o];
        const float sg = sigm(s);
#pragma unroll
        for (int vo = 0; vo < 4; ++vo) gp[vo] = fmaf(sg, w1_wsv[o * 4 + vo], gp[vo]);
        row[o] = fmaxf(s, 0.0f);                  // sr1 (vn region dead after C)
    }
    float g1[4];
#pragma unroll
    for (int vo = 0; vo < 4; ++vo) g1[vo] = sigm(gp[vo] + w1_wsvb[vo]);
    float v1g[12];
#pragma unroll
    for (int vo = 0; vo < 4; ++vo)
#pragma unroll
        for (int d = 0; d < 3; ++d) v1g[vo * 3 + d] = pv[vo * 3 + d] * g1[vo];
    // vh2[d][h] = sum_c v1g[c][d]*w2_wh[c][h]
    float vh2[12];
#pragma unroll
    for (int i = 0; i < 12; ++i) vh2[i] = 0.0f;
#pragma unroll
    for (int c = 0; c < 4; ++c)
#pragma unroll
        for (int h = 0; h < 4; ++h) {
            const float w = w2_wh[c * 4 + h];
#pragma unroll
            for (int d = 0; d < 3; ++d) vh2[d * 4 + h] = fmaf(v1g[c * 3 + d], w, vh2[d * 4 + h]);
        }
#pragma unroll
    for (int h = 0; h < 4; ++h) {
        const float ss = vh2[h] * vh2[h] + vh2[4 + h] * vh2[4 + h] + vh2[8 + h] * vh2[8 + h];
        row[64 + h] = sqrtf(fmaxf(ss, 1e-8f));    // vn2
    }

    // ---- E: GEMM2  s2[o] = sum_{k<68} [sr1|vn2][k]*w2_ws[k][o]
    float acc2[64];
#pragma unroll
    for (int o = 0; o < 64; ++o) acc2[o] = 0.0f;
    for (int k = 0; k < 68; ++k) {
        const float xk = row[k];
        const float* w = w2_ws + k * 64;
#pragma unroll
        for (int o = 0; o < 64; ++o) acc2[o] = fmaf(xk, w[o], acc2[o]);
    }

    // ---- F: layer-2 epilogue: gate2, v2 = (vh2@w2_wv)*g2, vh3, sr2 -> row[0..63], vn3 -> row[64..67]
    float gp2[4] = {0.f, 0.f, 0.f, 0.f};
#pragma unroll
    for (int o = 0; o < 64; ++o) {
        const float s = acc2[o] + w2_wsb[o];
        const float sg = sigm(s);
#pragma unroll
        for (int vo = 0; vo < 4; ++vo) gp2[vo] = fmaf(sg, w2_wsv[o * 4 + vo], gp2[vo]);
        row[o] = fmaxf(s, 0.0f);                  // sr2 (overwrites sr1 after E fully read it)
    }
    float g2[4];
#pragma unroll
    for (int vo = 0; vo < 4; ++vo) g2[vo] = sigm(gp2[vo] + w2_wsvb[vo]);
    float v2g[12];
#pragma unroll
    for (int vo = 0; vo < 4; ++vo)
#pragma unroll
        for (int d = 0; d < 3; ++d) {
            float t = 0.0f;
#pragma unroll
            for (int h = 0; h < 4; ++h) t = fmaf(vh2[d * 4 + h], w2_wv[h * 4 + vo], t);
            v2g[vo * 3 + d] = t * g2[vo];
        }
    float vh3[12];
#pragma unroll
    for (int i = 0; i < 12; ++i) vh3[i] = 0.0f;
#pragma unroll
    for (int c = 0; c < 4; ++c)
#pragma unroll
        for (int h = 0; h < 4; ++h) {
            const float w = w3_wh[c * 4 + h];
#pragma unroll
            for (int d = 0; d < 3; ++d) vh3[d * 4 + h] = fmaf(v2g[c * 3 + d], w, vh3[d * 4 + h]);
        }
#pragma unroll
    for (int h = 0; h < 4; ++h) {
        const float ss = vh3[h] * vh3[h] + vh3[4 + h] * vh3[4 + h] + vh3[8 + h] * vh3[8 + h];
        row[64 + h] = sqrtf(fmaxf(ss, 1e-8f));    // vn3
    }

    // ---- G: GEMM3  s3[o] = sum_{k<68} [sr2|vn3][k]*w3_ws[k][o]
#pragma unroll
    for (int o = 0; o < 64; ++o) acc[o] = 0.0f;   // reuse acc
    for (int k = 0; k < 68; ++k) {
        const float xk = row[k];
        const float* w = w3_ws + k * 64;
#pragma unroll
        for (int o = 0; o < 64; ++o) acc[o] = fmaf(xk, w[o], acc[o]);
    }

    // ---- H: final epilogue (no relu; gate_in = raw s3), atomics
    float gp3[4] = {0.f, 0.f, 0.f, 0.f};
#pragma unroll
    for (int o = 0; o < 64; ++o) {
        const float s3 = acc[o] + w3_wsb[o];
#pragma unroll
        for (int vo = 0; vo < 4; ++vo) gp3[vo] = fmaf(s3, w3_wsv[o * 4 + vo], gp3[vo]);
        atomicAdd(&out_s[(size_t)dst * 64 + o], s3);
    }
    float g3[4];
#pragma unroll
    for (int vo = 0; vo < 4; ++vo) g3[vo] = sigm(gp3[vo] + w3_wsvb[vo]);
#pragma unroll
    for (int vo = 0; vo < 4; ++vo)
#pragma unroll
        for (int d = 0; d < 3; ++d) {
            float t = 0.0f;
#pragma unroll
            for (int h = 0; h < 4; ++h) t = fmaf(vh3[d * 4 + h], w3_wv[h * 4 + vo], t);
            atomicAdd(&out_v[(size_t)dst * 12 + vo * 3 + d], t * g3[vo]);
        }
    atomicAdd(&cnt[dst], 1.0f);
}

// ---------------- finalize: mean, mask, cos/sin/exp, vector normalize ----------------
// recon_mask is a bool array in the reference -> harness passes integers as int32.
__global__ void gvp_finalize_kernel(float* __restrict__ out,
                                    const float* __restrict__ cnt,
                                    const int* __restrict__ mask, int N)
{
    const int g = blockIdx.x * blockDim.x + threadIdx.x;
    const int ns = N * 64;
    const int total = ns + N * 4;
    if (g >= total) return;
    if (g < ns) {
        const int n = g >> 6, j = g & 63;
        const float denom = fmaxf(cnt[n], 1.0f);
        const float m = (mask[n] != 0) ? 1.0f : 0.0f;
        const float s = out[g] / denom;
        const float r = (j < 7) ? __cosf(s) : (j < 14) ? __sinf(s) : __expf(s);
        out[g] = r * m;
    } else {
        const int g2 = g - ns;
        const int n = g2 >> 2, vo = g2 & 3;
        const float denom = fmaxf(cnt[n], 1.0f);
        const float m = (mask[n] != 0) ? 1.0f : 0.0f;
        float* vp = out + ns + (size_t)n * 12 + vo * 3;
        const float v0 = vp[0] / denom, v1 = vp[1] / denom, v2 = vp[2] / denom;
        const float mag = sqrtf(v0 * v0 + v1 * v1 + v2 * v2);
        const float inv = m / (mag + 1e-8f);
        vp[0] = v0 * inv; vp[1] = v1 * inv; vp[2] = v2 * inv;
    }
}

extern "C" void kernel_launch(void* const* d_in, const int* in_sizes, int n_in,
                              void* d_out, int out_size, void* d_ws, size_t ws_size,
                              hipStream_t stream)
{
    const float* node_s = (const float*)d_in[0];
    const float* node_v = (const float*)d_in[1];
    const int*   ei     = (const int*)d_in[2];
    const float* edge_s = (const float*)d_in[3];
    const float* edge_v = (const float*)d_in[4];
    const int*   mask   = (const int*)d_in[5];
    const float* w1_wh  = (const float*)d_in[6];
    const float* w1_ws  = (const float*)d_in[7];
    const float* w1_wsb = (const float*)d_in[8];
    const float* w1_wv  = (const float*)d_in[9];
    const float* w1_wsv = (const float*)d_in[10];
    const float* w1_wsvb= (const float*)d_in[11];
    const float* w2_wh  = (const float*)d_in[12];
    const float* w2_ws  = (const float*)d_in[13];
    const float* w2_wsb = (const float*)d_in[14];
    const float* w2_wv  = (const float*)d_in[15];
    const float* w2_wsv = (const float*)d_in[16];
    const float* w2_wsvb= (const float*)d_in[17];
    const float* w3_wh  = (const float*)d_in[18];
    const float* w3_ws  = (const float*)d_in[19];
    const float* w3_wsb = (const float*)d_in[20];
    const float* w3_wv  = (const float*)d_in[21];
    const float* w3_wsv = (const float*)d_in[22];
    const float* w3_wsvb= (const float*)d_in[23];

    const int N = in_sizes[0] / 128;   // 20000
    const int E = in_sizes[3] / 32;    // 320000

    float* out = (float*)d_out;
    float* cnt = (float*)d_ws;

    hipMemsetAsync(d_out, 0, (size_t)out_size * sizeof(float), stream);
    hipMemsetAsync(cnt, 0, (size_t)N * sizeof(float), stream);

    const int blocks = (E + THREADS - 1) / THREADS;   // 2500
    gvp_edge_kernel<<<blocks, THREADS, 0, stream>>>(
        node_s, node_v, ei, edge_s, edge_v,
        w1_wh, w1_ws, w1_wsb, w1_wv, w1_wsv, w1_wsvb,
        w2_wh, w2_ws, w2_wsb, w2_wv, w2_wsv, w2_wsvb,
        w3_wh, w3_ws, w3_wsb, w3_wv, w3_wsv, w3_wsvb,
        out, out + (size_t)N * 64, cnt, E);

    const int total2 = N * 68;
    gvp_finalize_kernel<<<(total2 + 255) / 256, 256, 0, stream>>>(out, cnt, mask, N);
}

// Round 7
// 1627.471 us; speedup vs baseline: 1.2483x; 1.2483x over previous
//
#include <hip/hip_runtime.h>
#include <math.h>

__device__ __forceinline__ float sigm(float x) { return 1.0f / (1.0f + __expf(-x)); }

// rank-4 update of acc[64] from one float4 of x and 4 weight rows (uniform addr -> s_load)
#define RANK4(XV, WPTR) do {                                                            \
    const float* w_ = (WPTR);                                                           \
    _Pragma("unroll") for (int o_ = 0; o_ < 64; ++o_) acc[o_] = fmaf((XV).x, w_[o_],       acc[o_]); \
    _Pragma("unroll") for (int o_ = 0; o_ < 64; ++o_) acc[o_] = fmaf((XV).y, w_[64 + o_],  acc[o_]); \
    _Pragma("unroll") for (int o_ = 0; o_ < 64; ++o_) acc[o_] = fmaf((XV).z, w_[128 + o_], acc[o_]); \
    _Pragma("unroll") for (int o_ = 0; o_ < 64; ++o_) acc[o_] = fmaf((XV).w, w_[192 + o_], acc[o_]); \
} while (0)

// ================= node precompute =================
// ys_a[n][64] = node_s[n] @ w1_ws[0:128]      (src role)
// ys_b[n][64] = node_s[n] @ w1_ws[160:288]    (dst role)
// va[n][3h+d] = sum_{c<16} node_v[n][c][d] * w1_wh[c][h]        (stride 100)
// vb[n][3h+d] = sum_{c<16} node_v[n][c][d] * w1_wh[17+c][h]     (stride 100)
__global__ __launch_bounds__(64) void node_pre_kernel(
    const float* __restrict__ node_s, const float* __restrict__ node_v,
    const float* __restrict__ w1_wh, const float* __restrict__ w1_ws,
    float* __restrict__ ysA, float* __restrict__ ysB,
    float* __restrict__ va, float* __restrict__ vb, int N)
{
    const int n = blockIdx.x * 64 + threadIdx.x;
    if (n >= N) return;

    // ---- vector part
    float v[48];
    {
        const float4* vs = (const float4*)(node_v + (size_t)n * 48);
#pragma unroll
        for (int j = 0; j < 12; ++j) {
            float4 t = vs[j];
            v[4 * j + 0] = t.x; v[4 * j + 1] = t.y; v[4 * j + 2] = t.z; v[4 * j + 3] = t.w;
        }
    }
    float* vaP = va + (size_t)n * 100;
    float* vbP = vb + (size_t)n * 100;
    for (int h = 0; h < 33; ++h) {           // rolled; weight addrs uniform
        const float* wc = w1_wh + h;
        float a0 = 0.f, a1 = 0.f, a2 = 0.f, b0 = 0.f, b1 = 0.f, b2 = 0.f;
#pragma unroll
        for (int c = 0; c < 16; ++c) {
            const float wa = wc[c * 33];
            const float wb = wc[(17 + c) * 33];
            a0 = fmaf(v[3 * c + 0], wa, a0); a1 = fmaf(v[3 * c + 1], wa, a1); a2 = fmaf(v[3 * c + 2], wa, a2);
            b0 = fmaf(v[3 * c + 0], wb, b0); b1 = fmaf(v[3 * c + 1], wb, b1); b2 = fmaf(v[3 * c + 2], wb, b2);
        }
        vaP[3 * h + 0] = a0; vaP[3 * h + 1] = a1; vaP[3 * h + 2] = a2;
        vbP[3 * h + 0] = b0; vbP[3 * h + 1] = b1; vbP[3 * h + 2] = b2;
    }

    // ---- scalar part (two sequential acc passes to cap VGPR)
    const float4* xs = (const float4*)(node_s + (size_t)n * 128);
    {
        float acc[64];
#pragma unroll
        for (int o = 0; o < 64; ++o) acc[o] = 0.0f;
        for (int k4 = 0; k4 < 32; ++k4) { float4 x = xs[k4]; RANK4(x, w1_ws + (k4 * 4) * 64); }
        float4* oa = (float4*)(ysA + (size_t)n * 64);
#pragma unroll
        for (int q = 0; q < 16; ++q) { float4 t; t.x = acc[4*q]; t.y = acc[4*q+1]; t.z = acc[4*q+2]; t.w = acc[4*q+3]; oa[q] = t; }
    }
    {
        float acc[64];
#pragma unroll
        for (int o = 0; o < 64; ++o) acc[o] = 0.0f;
        for (int k4 = 0; k4 < 32; ++k4) { float4 x = xs[k4]; RANK4(x, w1_ws + (160 + k4 * 4) * 64); }
        float4* ob = (float4*)(ysB + (size_t)n * 64);
#pragma unroll
        for (int q = 0; q < 16; ++q) { float4 t; t.x = acc[4*q]; t.y = acc[4*q+1]; t.z = acc[4*q+2]; t.w = acc[4*q+3]; ob[q] = t; }
    }
}

// ================= edge kernel (fast path) =================
__global__ __launch_bounds__(64) void gvp_edge_fast_kernel(
    const int* __restrict__ ei, const float* __restrict__ edge_s,
    const float* __restrict__ edge_v,
    const float* __restrict__ ysA, const float* __restrict__ ysB,
    const float* __restrict__ va, const float* __restrict__ vb,
    const float* __restrict__ w1_wh, const float* __restrict__ w1_ws,
    const float* __restrict__ w1_wsb, const float* __restrict__ w1_wv,
    const float* __restrict__ w1_wsv, const float* __restrict__ w1_wsvb,
    const float* __restrict__ w2_wh, const float* __restrict__ w2_ws,
    const float* __restrict__ w2_wsb, const float* __restrict__ w2_wv,
    const float* __restrict__ w2_wsv, const float* __restrict__ w2_wsvb,
    const float* __restrict__ w3_wh, const float* __restrict__ w3_ws,
    const float* __restrict__ w3_wsb, const float* __restrict__ w3_wv,
    const float* __restrict__ w3_wsv, const float* __restrict__ w3_wsvb,
    float* __restrict__ out_s, float* __restrict__ out_v,
    float* __restrict__ cnt, int E)
{
    __shared__ float rows[64 * 69];
    float* row = rows + threadIdx.x * 69;     // per-thread 69-float row (sr|vn)
    const int e = blockIdx.x * 64 + threadIdx.x;
    if (e >= E) return;
    const int src = ei[e];
    const int dst = ei[E + e];
    const float ev0 = edge_v[(size_t)e * 3 + 0];
    const float ev1 = edge_v[(size_t)e * 3 + 1];
    const float ev2 = edge_v[(size_t)e * 3 + 2];

    // ---- phase V: vh[h] = va_src + vb_dst + ev*we[h]; vn -> acc tail; pv accumulation
    float acc[64];
#pragma unroll
    for (int o = 0; o < 64; ++o) acc[o] = 0.0f;
    float pv[12];
#pragma unroll
    for (int i = 0; i < 12; ++i) pv[i] = 0.0f;

    const float* vaP = va + (size_t)src * 100;
    const float* vbP = vb + (size_t)dst * 100;
    for (int g = 0; g < 8; ++g) {            // h = 4g..4g+3
        float ca[12];
        {
            float4 A0 = *(const float4*)(vaP + g * 12 + 0);
            float4 A1 = *(const float4*)(vaP + g * 12 + 4);
            float4 A2 = *(const float4*)(vaP + g * 12 + 8);
            float4 B0 = *(const float4*)(vbP + g * 12 + 0);
            float4 B1 = *(const float4*)(vbP + g * 12 + 4);
            float4 B2 = *(const float4*)(vbP + g * 12 + 8);
            ca[0] = A0.x + B0.x; ca[1] = A0.y + B0.y; ca[2]  = A0.z + B0.z; ca[3]  = A0.w + B0.w;
            ca[4] = A1.x + B1.x; ca[5] = A1.y + B1.y; ca[6]  = A1.z + B1.z; ca[7]  = A1.w + B1.w;
            ca[8] = A2.x + B2.x; ca[9] = A2.y + B2.y; ca[10] = A2.z + B2.z; ca[11] = A2.w + B2.w;
        }
        const float* weP = w1_wh + 16 * 33 + 4 * g;        // uniform
        const float* wvP = w1_wv + (4 * g) * 4;            // uniform
        const float* wsP = w1_ws + (size_t)(288 + 4 * g) * 64;  // uniform
#pragma unroll
        for (int i = 0; i < 4; ++i) {
            const float we = weP[i];
            const float d0 = ca[3 * i + 0] + ev0 * we;
            const float d1 = ca[3 * i + 1] + ev1 * we;
            const float d2 = ca[3 * i + 2] + ev2 * we;
            const float vn = sqrtf(fmaxf(d0 * d0 + d1 * d1 + d2 * d2, 1e-8f));
            const float* wr = wsP + i * 64;
#pragma unroll
            for (int o = 0; o < 64; ++o) acc[o] = fmaf(vn, wr[o], acc[o]);
#pragma unroll
            for (int vo = 0; vo < 4; ++vo) {
                const float w = wvP[i * 4 + vo];
                pv[vo * 3 + 0] = fmaf(d0, w, pv[vo * 3 + 0]);
                pv[vo * 3 + 1] = fmaf(d1, w, pv[vo * 3 + 1]);
                pv[vo * 3 + 2] = fmaf(d2, w, pv[vo * 3 + 2]);
            }
        }
    }
    {   // tail h = 32
        float4 A = *(const float4*)(vaP + 96);
        float4 B = *(const float4*)(vbP + 96);
        const float we = w1_wh[16 * 33 + 32];
        const float d0 = A.x + B.x + ev0 * we;
        const float d1 = A.y + B.y + ev1 * we;
        const float d2 = A.z + B.z + ev2 * we;
        const float vn = sqrtf(fmaxf(d0 * d0 + d1 * d1 + d2 * d2, 1e-8f));
        const float* wr = w1_ws + (size_t)320 * 64;
#pragma unroll
        for (int o = 0; o < 64; ++o) acc[o] = fmaf(vn, wr[o], acc[o]);
#pragma unroll
        for (int vo = 0; vo < 4; ++vo) {
            const float w = w1_wv[32 * 4 + vo];
            pv[vo * 3 + 0] = fmaf(d0, w, pv[vo * 3 + 0]);
            pv[vo * 3 + 1] = fmaf(d1, w, pv[vo * 3 + 1]);
            pv[vo * 3 + 2] = fmaf(d2, w, pv[vo * 3 + 2]);
        }
    }

    // ---- add precomputed node terms
    {
        const float4* pa = (const float4*)(ysA + (size_t)src * 64);
        const float4* pb = (const float4*)(ysB + (size_t)dst * 64);
#pragma unroll
        for (int q = 0; q < 16; ++q) {
            float4 xa = pa[q], xb = pb[q];
            acc[4 * q + 0] += xa.x + xb.x;
            acc[4 * q + 1] += xa.y + xb.y;
            acc[4 * q + 2] += xa.z + xb.z;
            acc[4 * q + 3] += xa.w + xb.w;
        }
    }
    // ---- edge_s @ w1_ws[128:160]
    {
        const float4* xs = (const float4*)(edge_s + (size_t)e * 32);
        for (int k4 = 0; k4 < 8; ++k4) { float4 x = xs[k4]; RANK4(x, w1_ws + (size_t)(128 + k4 * 4) * 64); }
    }

    // ---- layer-1 epilogue: gate1, relu -> row[0..63], vn2 -> row[64..67]
    float gp[4] = {0.f, 0.f, 0.f, 0.f};
#pragma unroll
    for (int o = 0; o < 64; ++o) {
        const float s = acc[o] + w1_wsb[o];
        const float sg = sigm(s);
#pragma unroll
        for (int vo = 0; vo < 4; ++vo) gp[vo] = fmaf(sg, w1_wsv[o * 4 + vo], gp[vo]);
        row[o] = fmaxf(s, 0.0f);
    }
    float g1[4];
#pragma unroll
    for (int vo = 0; vo < 4; ++vo) g1[vo] = sigm(gp[vo] + w1_wsvb[vo]);
    float v1g[12];
#pragma unroll
    for (int vo = 0; vo < 4; ++vo)
#pragma unroll
        for (int d = 0; d < 3; ++d) v1g[vo * 3 + d] = pv[vo * 3 + d] * g1[vo];
    float vh2[12];
#pragma unroll
    for (int i = 0; i < 12; ++i) vh2[i] = 0.0f;
#pragma unroll
    for (int c = 0; c < 4; ++c)
#pragma unroll
        for (int h = 0; h < 4; ++h) {
            const float w = w2_wh[c * 4 + h];
#pragma unroll
            for (int d = 0; d < 3; ++d) vh2[d * 4 + h] = fmaf(v1g[c * 3 + d], w, vh2[d * 4 + h]);
        }
#pragma unroll
    for (int h = 0; h < 4; ++h) {
        const float ss = vh2[h] * vh2[h] + vh2[4 + h] * vh2[4 + h] + vh2[8 + h] * vh2[8 + h];
        row[64 + h] = sqrtf(fmaxf(ss, 1e-8f));
    }

    // ---- GEMM2
    float acc2[64];
#pragma unroll
    for (int o = 0; o < 64; ++o) acc2[o] = 0.0f;
    for (int k = 0; k < 68; ++k) {
        const float xk = row[k];
        const float* w = w2_ws + k * 64;
#pragma unroll
        for (int o = 0; o < 64; ++o) acc2[o] = fmaf(xk, w[o], acc2[o]);
    }

    // ---- layer-2 epilogue
    float gp2[4] = {0.f, 0.f, 0.f, 0.f};
#pragma unroll
    for (int o = 0; o < 64; ++o) {
        const float s = acc2[o] + w2_wsb[o];
        const float sg = sigm(s);
#pragma unroll
        for (int vo = 0; vo < 4; ++vo) gp2[vo] = fmaf(sg, w2_wsv[o * 4 + vo], gp2[vo]);
        row[o] = fmaxf(s, 0.0f);
    }
    float g2[4];
#pragma unroll
    for (int vo = 0; vo < 4; ++vo) g2[vo] = sigm(gp2[vo] + w2_wsvb[vo]);
    float v2g[12];
#pragma unroll
    for (int vo = 0; vo < 4; ++vo)
#pragma unroll
        for (int d = 0; d < 3; ++d) {
            float t = 0.0f;
#pragma unroll
            for (int h = 0; h < 4; ++h) t = fmaf(vh2[d * 4 + h], w2_wv[h * 4 + vo], t);
            v2g[vo * 3 + d] = t * g2[vo];
        }
    float vh3[12];
#pragma unroll
    for (int i = 0; i < 12; ++i) vh3[i] = 0.0f;
#pragma unroll
    for (int c = 0; c < 4; ++c)
#pragma unroll
        for (int h = 0; h < 4; ++h) {
            const float w = w3_wh[c * 4 + h];
#pragma unroll
            for (int d = 0; d < 3; ++d) vh3[d * 4 + h] = fmaf(v2g[c * 3 + d], w, vh3[d * 4 + h]);
        }
#pragma unroll
    for (int h = 0; h < 4; ++h) {
        const float ss = vh3[h] * vh3[h] + vh3[4 + h] * vh3[4 + h] + vh3[8 + h] * vh3[8 + h];
        row[64 + h] = sqrtf(fmaxf(ss, 1e-8f));
    }

    // ---- GEMM3
#pragma unroll
    for (int o = 0; o < 64; ++o) acc[o] = 0.0f;
    for (int k = 0; k < 68; ++k) {
        const float xk = row[k];
        const float* w = w3_ws + k * 64;
#pragma unroll
        for (int o = 0; o < 64; ++o) acc[o] = fmaf(xk, w[o], acc[o]);
    }

    // ---- final epilogue + atomics
    float gp3[4] = {0.f, 0.f, 0.f, 0.f};
#pragma unroll
    for (int o = 0; o < 64; ++o) {
        const float s3 = acc[o] + w3_wsb[o];
#pragma unroll
        for (int vo = 0; vo < 4; ++vo) gp3[vo] = fmaf(s3, w3_wsv[o * 4 + vo], gp3[vo]);
        atomicAdd(&out_s[(size_t)dst * 64 + o], s3);
    }
    float g3[4];
#pragma unroll
    for (int vo = 0; vo < 4; ++vo) g3[vo] = sigm(gp3[vo] + w3_wsvb[vo]);
#pragma unroll
    for (int vo = 0; vo < 4; ++vo)
#pragma unroll
        for (int d = 0; d < 3; ++d) {
            float t = 0.0f;
#pragma unroll
            for (int h = 0; h < 4; ++h) t = fmaf(vh3[d * 4 + h], w3_wv[h * 4 + vo], t);
            atomicAdd(&out_v[(size_t)dst * 12 + vo * 3 + d], t * g3[vo]);
        }
    atomicAdd(&cnt[dst], 1.0f);
}

// ================= legacy edge kernel (round-3 passing version; fallback if ws too small) =================
__global__ __launch_bounds__(128) void gvp_edge_kernel(
    const float* __restrict__ node_s, const float* __restrict__ node_v,
    const int* __restrict__ ei, const float* __restrict__ edge_s,
    const float* __restrict__ edge_v,
    const float* __restrict__ w1_wh, const float* __restrict__ w1_ws,
    const float* __restrict__ w1_wsb, const float* __restrict__ w1_wv,
    const float* __restrict__ w1_wsv, const float* __restrict__ w1_wsvb,
    const float* __restrict__ w2_wh, const float* __restrict__ w2_ws,
    const float* __restrict__ w2_wsb, const float* __restrict__ w2_wv,
    const float* __restrict__ w2_wsv, const float* __restrict__ w2_wsvb,
    const float* __restrict__ w3_wh, const float* __restrict__ w3_ws,
    const float* __restrict__ w3_wsb, const float* __restrict__ w3_wv,
    const float* __restrict__ w3_wsv, const float* __restrict__ w3_wsvb,
    float* __restrict__ out_s, float* __restrict__ out_v,
    float* __restrict__ cnt, int E)
{
    __shared__ float rows[128 * 99];
    float* row = rows + threadIdx.x * 99;
    const int e = blockIdx.x * 128 + threadIdx.x;
    if (e >= E) return;
    const int src = ei[e];
    const int dst = ei[E + e];
    {
        const float* a = node_v + (size_t)src * 48;
        const float* b = node_v + (size_t)dst * 48;
#pragma unroll
        for (int j = 0; j < 48; j += 4) {
            float4 vav = *(const float4*)(a + j);
            row[j + 0] = vav.x; row[j + 1] = vav.y; row[j + 2] = vav.z; row[j + 3] = vav.w;
            float4 vbv = *(const float4*)(b + j);
            row[48 + j + 0] = vbv.x; row[48 + j + 1] = vbv.y; row[48 + j + 2] = vbv.z; row[48 + j + 3] = vbv.w;
        }
        row[96] = edge_v[(size_t)e * 3 + 0];
        row[97] = edge_v[(size_t)e * 3 + 1];
        row[98] = edge_v[(size_t)e * 3 + 2];
    }
    float vn[33];
    float pv[12];
#pragma unroll
    for (int i = 0; i < 12; ++i) pv[i] = 0.0f;
#pragma unroll
    for (int p = 0; p < 3; ++p) {
        const int h0 = p * 11;
        float a0[11], a1[11], a2[11];
#pragma unroll
        for (int i = 0; i < 11; ++i) { a0[i] = 0.f; a1[i] = 0.f; a2[i] = 0.f; }
        for (int c = 0; c < 16; ++c) {
            const float v0 = row[3 * c + 0], v1 = row[3 * c + 1], v2 = row[3 * c + 2];
            const float* wr = w1_wh + c * 33 + h0;
#pragma unroll
            for (int i = 0; i < 11; ++i) {
                const float w = wr[i];
                a0[i] = fmaf(v0, w, a0[i]); a1[i] = fmaf(v1, w, a1[i]); a2[i] = fmaf(v2, w, a2[i]);
            }
        }
        for (int c = 0; c < 16; ++c) {
            const float v0 = row[48 + 3 * c + 0], v1 = row[48 + 3 * c + 1], v2 = row[48 + 3 * c + 2];
            const float* wr = w1_wh + (17 + c) * 33 + h0;
#pragma unroll
            for (int i = 0; i < 11; ++i) {
                const float w = wr[i];
                a0[i] = fmaf(v0, w, a0[i]); a1[i] = fmaf(v1, w, a1[i]); a2[i] = fmaf(v2, w, a2[i]);
            }
        }
        {
            const float v0 = row[96], v1 = row[97], v2 = row[98];
            const float* wr = w1_wh + 16 * 33 + h0;
#pragma unroll
            for (int i = 0; i < 11; ++i) {
                const float w = wr[i];
                a0[i] = fmaf(v0, w, a0[i]); a1[i] = fmaf(v1, w, a1[i]); a2[i] = fmaf(v2, w, a2[i]);
            }
        }
#pragma unroll
        for (int i = 0; i < 11; ++i) {
            const int h = h0 + i;
            vn[h] = sqrtf(fmaxf(a0[i] * a0[i] + a1[i] * a1[i] + a2[i] * a2[i], 1e-8f));
#pragma unroll
            for (int vo = 0; vo < 4; ++vo) {
                const float w = w1_wv[h * 4 + vo];
                pv[vo * 3 + 0] = fmaf(a0[i], w, pv[vo * 3 + 0]);
                pv[vo * 3 + 1] = fmaf(a1[i], w, pv[vo * 3 + 1]);
                pv[vo * 3 + 2] = fmaf(a2[i], w, pv[vo * 3 + 2]);
            }
        }
    }
#pragma unroll
    for (int h = 0; h < 33; ++h) row[h] = vn[h];
    float acc[64];
#pragma unroll
    for (int o = 0; o < 64; ++o) acc[o] = 0.0f;
    {
        const float4* xs = (const float4*)(node_s + (size_t)src * 128);
        for (int k4 = 0; k4 < 32; ++k4) { float4 x = xs[k4]; RANK4(x, w1_ws + (k4 * 4) * 64); }
    }
    {
        const float4* xs = (const float4*)(edge_s + (size_t)e * 32);
        for (int k4 = 0; k4 < 8; ++k4)  { float4 x = xs[k4]; RANK4(x, w1_ws + (128 + k4 * 4) * 64); }
    }
    {
        const float4* xs = (const float4*)(node_s + (size_t)dst * 128);
        for (int k4 = 0; k4 < 32; ++k4) { float4 x = xs[k4]; RANK4(x, w1_ws + (160 + k4 * 4) * 64); }
    }
    for (int h = 0; h < 33; ++h) {
        const float xk = row[h];
        const float* w = w1_ws + (288 + h) * 64;
#pragma unroll
        for (int o = 0; o < 64; ++o) acc[o] = fmaf(xk, w[o], acc[o]);
    }
    float gp[4] = {0.f, 0.f, 0.f, 0.f};
#pragma unroll
    for (int o = 0; o < 64; ++o) {
        const float s = acc[o] + w1_wsb[o];
        const float sg = sigm(s);
#pragma unroll
        for (int vo = 0; vo < 4; ++vo) gp[vo] = fmaf(sg, w1_wsv[o * 4 + vo], gp[vo]);
        row[o] = fmaxf(s, 0.0f);
    }
    float g1[4];
#pragma unroll
    for (int vo = 0; vo < 4; ++vo) g1[vo] = sigm(gp[vo] + w1_wsvb[vo]);
    float v1g[12];
#pragma unroll
    for (int vo = 0; vo < 4; ++vo)
#pragma unroll
        for (int d = 0; d < 3; ++d) v1g[vo * 3 + d] = pv[vo * 3 + d] * g1[vo];
    float vh2[12];
#pragma unroll
    for (int i = 0; i < 12; ++i) vh2[i] = 0.0f;
#pragma unroll
    for (int c = 0; c < 4; ++c)
#pragma unroll
        for (int h = 0; h < 4; ++h) {
            const float w = w2_wh[c * 4 + h];
#pragma unroll
            for (int d = 0; d < 3; ++d) vh2[d * 4 + h] = fmaf(v1g[c * 3 + d], w, vh2[d * 4 + h]);
        }
#pragma unroll
    for (int h = 0; h < 4; ++h) {
        const float ss = vh2[h] * vh2[h] + vh2[4 + h] * vh2[4 + h] + vh2[8 + h] * vh2[8 + h];
        row[64 + h] = sqrtf(fmaxf(ss, 1e-8f));
    }
    float acc2[64];
#pragma unroll
    for (int o = 0; o < 64; ++o) acc2[o] = 0.0f;
    for (int k = 0; k < 68; ++k) {
        const float xk = row[k];
        const float* w = w2_ws + k * 64;
#pragma unroll
        for (int o = 0; o < 64; ++o) acc2[o] = fmaf(xk, w[o], acc2[o]);
    }
    float gp2[4] = {0.f, 0.f, 0.f, 0.f};
#pragma unroll
    for (int o = 0; o < 64; ++o) {
        const float s = acc2[o] + w2_wsb[o];
        const float sg = sigm(s);
#pragma unroll
        for (int vo = 0; vo < 4; ++vo) gp2[vo] = fmaf(sg, w2_wsv[o * 4 + vo], gp2[vo]);
        row[o] = fmaxf(s, 0.0f);
    }
    float g2[4];
#pragma unroll
    for (int vo = 0; vo < 4; ++vo) g2[vo] = sigm(gp2[vo] + w2_wsvb[vo]);
    float v2g[12];
#pragma unroll
    for (int vo = 0; vo < 4; ++vo)
#pragma unroll
        for (int d = 0; d < 3; ++d) {
            float t = 0.0f;
#pragma unroll
            for (int h = 0; h < 4; ++h) t = fmaf(vh2[d * 4 + h], w2_wv[h * 4 + vo], t);
            v2g[vo * 3 + d] = t * g2[vo];
        }
    float vh3[12];
#pragma unroll
    for (int i = 0; i < 12; ++i) vh3[i] = 0.0f;
#pragma unroll
    for (int c = 0; c < 4; ++c)
#pragma unroll
        for (int h = 0; h < 4; ++h) {
            const float w = w3_wh[c * 4 + h];
#pragma unroll
            for (int d = 0; d < 3; ++d) vh3[d * 4 + h] = fmaf(v2g[c * 3 + d], w, vh3[d * 4 + h]);
        }
#pragma unroll
    for (int h = 0; h < 4; ++h) {
        const float ss = vh3[h] * vh3[h] + vh3[4 + h] * vh3[4 + h] + vh3[8 + h] * vh3[8 + h];
        row[64 + h] = sqrtf(fmaxf(ss, 1e-8f));
    }
#pragma unroll
    for (int o = 0; o < 64; ++o) acc[o] = 0.0f;
    for (int k = 0; k < 68; ++k) {
        const float xk = row[k];
        const float* w = w3_ws + k * 64;
#pragma unroll
        for (int o = 0; o < 64; ++o) acc[o] = fmaf(xk, w[o], acc[o]);
    }
    float gp3[4] = {0.f, 0.f, 0.f, 0.f};
#pragma unroll
    for (int o = 0; o < 64; ++o) {
        const float s3 = acc[o] + w3_wsb[o];
#pragma unroll
        for (int vo = 0; vo < 4; ++vo) gp3[vo] = fmaf(s3, w3_wsv[o * 4 + vo], gp3[vo]);
        atomicAdd(&out_s[(size_t)dst * 64 + o], s3);
    }
    float g3[4];
#pragma unroll
    for (int vo = 0; vo < 4; ++vo) g3[vo] = sigm(gp3[vo] + w3_wsvb[vo]);
#pragma unroll
    for (int vo = 0; vo < 4; ++vo)
#pragma unroll
        for (int d = 0; d < 3; ++d) {
            float t = 0.0f;
#pragma unroll
            for (int h = 0; h < 4; ++h) t = fmaf(vh3[d * 4 + h], w3_wv[h * 4 + vo], t);
            atomicAdd(&out_v[(size_t)dst * 12 + vo * 3 + d], t * g3[vo]);
        }
    atomicAdd(&cnt[dst], 1.0f);
}

// ================= finalize =================
__global__ void gvp_finalize_kernel(float* __restrict__ out,
                                    const float* __restrict__ cnt,
                                    const int* __restrict__ mask, int N)
{
    const int g = blockIdx.x * blockDim.x + threadIdx.x;
    const int ns = N * 64;
    const int total = ns + N * 4;
    if (g >= total) return;
    if (g < ns) {
        const int n = g >> 6, j = g & 63;
        const float denom = fmaxf(cnt[n], 1.0f);
        const float m = (mask[n] != 0) ? 1.0f : 0.0f;
        const float s = out[g] / denom;
        const float r = (j < 7) ? __cosf(s) : (j < 14) ? __sinf(s) : __expf(s);
        out[g] = r * m;
    } else {
        const int g2 = g - ns;
        const int n = g2 >> 2, vo = g2 & 3;
        const float denom = fmaxf(cnt[n], 1.0f);
        const float m = (mask[n] != 0) ? 1.0f : 0.0f;
        float* vp = out + ns + (size_t)n * 12 + vo * 3;
        const float v0 = vp[0] / denom, v1 = vp[1] / denom, v2 = vp[2] / denom;
        const float mag = sqrtf(v0 * v0 + v1 * v1 + v2 * v2);
        const float inv = m / (mag + 1e-8f);
        vp[0] = v0 * inv; vp[1] = v1 * inv; vp[2] = v2 * inv;
    }
}

extern "C" void kernel_launch(void* const* d_in, const int* in_sizes, int n_in,
                              void* d_out, int out_size, void* d_ws, size_t ws_size,
                              hipStream_t stream)
{
    const float* node_s = (const float*)d_in[0];
    const float* node_v = (const float*)d_in[1];
    const int*   ei     = (const int*)d_in[2];
    const float* edge_s = (const float*)d_in[3];
    const float* edge_v = (const float*)d_in[4];
    const int*   mask   = (const int*)d_in[5];
    const float* w1_wh  = (const float*)d_in[6];
    const float* w1_ws  = (const float*)d_in[7];
    const float* w1_wsb = (const float*)d_in[8];
    const float* w1_wv  = (const float*)d_in[9];
    const float* w1_wsv = (const float*)d_in[10];
    const float* w1_wsvb= (const float*)d_in[11];
    const float* w2_wh  = (const float*)d_in[12];
    const float* w2_ws  = (const float*)d_in[13];
    const float* w2_wsb = (const float*)d_in[14];
    const float* w2_wv  = (const float*)d_in[15];
    const float* w2_wsv = (const float*)d_in[16];
    const float* w2_wsvb= (const float*)d_in[17];
    const float* w3_wh  = (const float*)d_in[18];
    const float* w3_ws  = (const float*)d_in[19];
    const float* w3_wsb = (const float*)d_in[20];
    const float* w3_wv  = (const float*)d_in[21];
    const float* w3_wsv = (const float*)d_in[22];
    const float* w3_wsvb= (const float*)d_in[23];

    const int N = in_sizes[0] / 128;   // 20000
    const int E = in_sizes[3] / 32;    // 320000

    float* out = (float*)d_out;
    float* ws  = (float*)d_ws;

    // ws layout (floats): ysA[N*64] | ysB[N*64] | va[N*100] | vb[N*100] | cnt[N]
    const size_t oYA = 0;
    const size_t oYB = (size_t)N * 64;
    const size_t oVA = oYB + (size_t)N * 64;
    const size_t oVB = oVA + (size_t)N * 100;
    const size_t oCN = oVB + (size_t)N * 100;
    const size_t needF = oCN + (size_t)N;
    const bool fast = (ws_size >= needF * sizeof(float));

    hipMemsetAsync(d_out, 0, (size_t)out_size * sizeof(float), stream);

    if (fast) {
        float* cnt = ws + oCN;
        hipMemsetAsync(cnt, 0, (size_t)N * sizeof(float), stream);
        node_pre_kernel<<<(N + 63) / 64, 64, 0, stream>>>(
            node_s, node_v, w1_wh, w1_ws,
            ws + oYA, ws + oYB, ws + oVA, ws + oVB, N);
        gvp_edge_fast_kernel<<<(E + 63) / 64, 64, 0, stream>>>(
            ei, edge_s, edge_v,
            ws + oYA, ws + oYB, ws + oVA, ws + oVB,
            w1_wh, w1_ws, w1_wsb, w1_wv, w1_wsv, w1_wsvb,
            w2_wh, w2_ws, w2_wsb, w2_wv, w2_wsv, w2_wsvb,
            w3_wh, w3_ws, w3_wsb, w3_wv, w3_wsv, w3_wsvb,
            out, out + (size_t)N * 64, cnt, E);
        const int total2 = N * 68;
        gvp_finalize_kernel<<<(total2 + 255) / 256, 256, 0, stream>>>(out, cnt, mask, N);
    } else {
        float* cnt = ws;
        hipMemsetAsync(cnt, 0, (size_t)N * sizeof(float), stream);
        gvp_edge_kernel<<<(E + 127) / 128, 128, 0, stream>>>(
            node_s, node_v, ei, edge_s, edge_v,
            w1_wh, w1_ws, w1_wsb, w1_wv, w1_wsv, w1_wsvb,
            w2_wh, w2_ws, w2_wsb, w2_wv, w2_wsv, w2_wsvb,
            w3_wh, w3_ws, w3_wsb, w3_wv, w3_wsv, w3_wsvb,
            out, out + (size_t)N * 64, cnt, E);
        const int total2 = N * 68;
        gvp_finalize_kernel<<<(total2 + 255) / 256, 256, 0, stream>>>(out, cnt, mask, N);
    }
}